// Round 18
// baseline (107.927 us; speedup 1.0000x reference)
//
#include <hip/hip_runtime.h>
#include <math.h>

#define MQ 1000
#define PI_F 3.14159265358979323846f
#define EPSF 1e-12f
#define DYF  ((float)(0.998/999.0))   // main y-grid step
#define DY2F ((float)(0.999/999.0))   // disconnected y2-grid step (= 0.001)
#define NG   2048                     // scan-grid points per function
#define HG   (0.998f / (float)NG)     // scan-grid step
#define ZT   0.02f                    // V-interp threshold: below this, exact quad

// fast HW approx ops (v_rcp_f32 / v_rsq_f32 / v_sqrt_f32, ~1 ulp)
__device__ __forceinline__ float frcp(float x)  { return __builtin_amdgcn_rcpf(x); }
__device__ __forceinline__ float frsq(float x)  { return __builtin_amdgcn_rsqf(x); }
__device__ __forceinline__ float fsqrt(float x) { return __builtin_amdgcn_sqrtf(x); }

// ws layout: [16 .. 16+NG)        = dL grid
//            [16+NG .. 16+2NG)    = V grid
//            [16+2NG .. 16+3NG)   = L grid (monotone for z < zs_max)
//            grid z_i = 0.001 + (i+0.5)*HG

// ---------------------------------------------------------------------------
struct Co {
    float q1, q2, q3, q4, cf4;
    float e1, e2, e3, e4;
    float b0, b1, p3;
    float coef;
};

__device__ __forceinline__ Co make_co(const float* a, const float* b, const float* lc) {
    Co c;
    float a0 = a[0], a1 = a[1];
    float cf1 = -8.f * a0 / 3.f;
    float cf2 = -2.f * (2.f * a1 + a0 * a0);
    float cf3 = -8.f * a0 * a1;
    c.cf4 = -4.f * a1 * a1;
    c.q1 = -cf1; c.q2 = -cf2; c.q3 = -cf3; c.q4 = cf1 + cf2 + cf3 - 1.f;
    c.e1 = 2.f * a0;
    c.e2 = 2.f * a1 + a0 * a0;
    c.e3 = 2.f * a0 * a1;
    c.e4 = a1 * a1;
    c.b0 = b[0]; c.b1 = b[1];
    c.p3 = a0 + a1 - b[0] - b[1];
    c.coef = expf(lc[0]);
    return c;
}

struct Uni { float zs, fs, rfs, A4; };

__device__ __forceinline__ Uni make_uni(const Co& c, float zs) {
    Uni U; U.zs = zs;
    float z = zs;
    float lg = __logf(z);
    float t4 = c.q4 + c.cf4 * lg;
    float fz = 1.f + z * (c.q1 + z * (c.q2 + z * (c.q3 + z * t4)));
    float s  = 1.f + z * (c.e1 + z * (c.e2 + z * (c.e3 + z * c.e4)));
    U.fs = fz;
    U.rfs = frcp(fz);
    float dfs = 4.f * (fz - s) * frcp(z);
    U.A4 = zs * dfs * U.rfs - 2.f;     // (zs dfs/fs + 2) - 4
    return U;
}

__device__ __forceinline__ void point_LdL(const Co& c, const Uni& U,
                                          float y, float u,
                                          float& iL, float& iD) {
    float u2  = u * u;
    float ru2 = frcp(u2);
    float ru4 = ru2 * ru2;
    float z  = U.zs * u;
    float z2 = z * z, z4 = z2 * z2;
    float lg = __logf(z);
    float t4 = c.q4 + c.cf4 * lg;
    float fz = 1.f + z * (c.q1 + z * (c.q2 + z * (c.q3 + z * t4)));
    float s  = 1.f + z * (c.e1 + z * (c.e2 + z * (c.e3 + z * c.e4)));
    float P  = 1.f + z * (c.b0 + z * (c.b1 + z * c.p3));
    float dP = c.b0 + z * (2.f * c.b1 + z * (3.f * c.p3));
    float D  = 1.f - z4;
    float rsqD = frsq(D);
    float rcpD = rsqD * rsqD;
    float rcpP = frcp(P);
    float zdgg = 2.f * z * dP * rcpP + 4.f * z4 * rcpD;   // z dg / g
    float F4 = fz * U.rfs * ru4;                          // r4 * f/fs
    float S4 = s  * U.rfs * ru4;
    float den = fmaxf(F4 - 1.f, EPSF);
    float rs  = frsq(den);
    float sqg = P * rsqD;
    float t1  = sqg * rs;
    iL = t1 * y;
    float t = F4 * (U.A4 + zdgg) + 4.f * S4 - 2.f - zdgg;
    float rs2 = rs * rs;
    iD = t * (2.f * y) * (t1 * rs2);                      // sqrt(1-z/zs) = y
}

__device__ __forceinline__ float point_Vc(const Co& c, const Uni& U,
                                          float y, float u) {
    float u2  = u * u;
    float u4  = u2 * u2;
    float ru2 = frcp(u2);
    float z  = U.zs * u;
    float z2 = z * z, z4 = z2 * z2;
    float lg = __logf(z);
    float t4 = c.q4 + c.cf4 * lg;
    float fz = 1.f + z * (c.q1 + z * (c.q2 + z * (c.q3 + z * t4)));
    float P  = 1.f + z * (c.b0 + z * (c.b1 + z * c.p3));
    float D  = 1.f - z4;
    float rsqD = frsq(D);
    float rcpD = rsqD * rsqD;
    float fg = fz * P * P * rcpD;
    float sqfg = fsqrt(fmaxf(fg, EPSF));
    float rfz = frcp(fz);
    float arg = fmaxf(1.f - u4 * U.fs * rfz, EPSF);
    float t = frsq(arg) - 1.f;
    return sqfg * ru2 * t * y;
}

__device__ __forceinline__ float point_Vd(const Co& c, const Uni& U, float y2) {
    float z  = 1.f - (1.f - U.zs) * y2;
    float z2 = z * z, z4 = z2 * z2;
    float lg = __logf(z);
    float t4 = c.q4 + c.cf4 * lg;
    float fz = 1.f + z * (c.q1 + z * (c.q2 + z * (c.q3 + z * t4)));
    float P  = 1.f + z * (c.b0 + z * (c.b1 + z * c.p3));
    float D  = 1.f - z4;
    float rsqD = frsq(D);
    float fg = fz * P * P * (rsqD * rsqD);
    float sq = fsqrt(fmaxf(fg, EPSF));
    float rz = frcp(z);
    return sq * rz * rz;
}

__device__ __forceinline__ float trapz_ext(float S, float i0, float i1, float iN) {
    float slope = (i1 - i0) * frcp(DYF);
    float v0 = i0 - slope * 0.001f;
    float yLast = 0.001f + 999.f * DYF;
    return DYF * (S - 0.5f * (i0 + iN))
         + 0.5f * (v0 + i0) * 0.001f
         + 0.5f * iN * (1.f - yLast);
}

__device__ __forceinline__ float trapz_d(float S, float q0, float qN) {
    return 0.5f * (1.f + q0) * 0.001f + DY2F * (S - 0.5f * (q0 + qN));
}

// wave-local V quadrature (16 pts/lane; j==0,1 -> k=0 lanes 0,1; j==999 ->
// k=15 lane 39).  All lanes return the same value.
__device__ __forceinline__ float wave_V(const Co& c, const Uni& U, int lane) {
    float sc = 0.f, sd = 0.f, c0 = 0.f, cN = 0.f, q0 = 0.f, qN = 0.f;
#pragma unroll
    for (int k = 0; k < 16; ++k) {
        if (k < 15 || lane < 40) {
            int j = lane + 64 * k;
            float y = fmaf((float)j, DYF, 0.001f);
            float u = 1.f - y * y;
            float vc = point_Vc(c, U, y, u);
            float y2 = fmaf((float)j, DY2F, 0.001f);
            float vd = point_Vd(c, U, y2);
            sc += vc; sd += vd;
            if (k == 0)  { c0 = vc; q0 = vd; }
            if (k == 15) { cN = vc; qN = vd; }
        }
    }
#pragma unroll
    for (int o = 32; o > 0; o >>= 1) {
        sc += __shfl_xor(sc, o, 64);
        sd += __shfl_xor(sd, o, 64);
    }
    float i0 = __shfl(c0, 0, 64), i1 = __shfl(c0, 1, 64), iN = __shfl(cN, 39, 64);
    float p0 = __shfl(q0, 0, 64), pN = __shfl(qN, 39, 64);
    float Vc = c.coef * PI_F * 4.f * trapz_ext(sc, i0, i1, iN) * frcp(U.zs);
    float Vd = c.coef * PI_F * 2.f * (1.f - U.zs) * trapz_d(sd, p0, pN);
    return Vc - Vd;
}

// ---------------------------------------------------------------------------
// Kernel A: grid evaluation, 2 waves (128 threads) per grid point.
// Block i<NG: L and dL at z_i; block i>=NG: V at z_{i-NG}.
// j = t + 128k; j=0,1 -> t=0,1 (k=0); j=999 -> t=103 (k=7).
// ---------------------------------------------------------------------------
__global__ __launch_bounds__(128) void grid_eval_kernel(
        const float* a, const float* b, const float* lc, float* ws) {
    __shared__ float red[4];
    __shared__ float spx[8];
    int bid = blockIdx.x;
    int t = threadIdx.x, lane = t & 63, w = t >> 6;
    Co c = make_co(a, b, lc);
    int i = (bid < NG) ? bid : bid - NG;
    float zq = fmaf((float)i + 0.5f, HG, 0.001f);
    Uni U = make_uni(c, zq);

    if (bid < NG) {
        float sL = 0.f, sD = 0.f, l0 = 0.f, d0 = 0.f, l1 = 0.f, d1 = 0.f,
              lN = 0.f, dN = 0.f;
#pragma unroll
        for (int k = 0; k < 8; ++k) {
            if (k < 7 || t < 104) {
                int j = t + 128 * k;
                float y = fmaf((float)j, DYF, 0.001f);
                float u = 1.f - y * y;
                float iL, iD;
                point_LdL(c, U, y, u, iL, iD);
                sL += iL; sD += iD;
                if (k == 0) {
                    if (t == 0) { l0 = iL; d0 = iD; }
                    if (t == 1) { l1 = iL; d1 = iD; }
                }
                if (k == 7 && t == 103) { lN = iL; dN = iD; }
            }
        }
#pragma unroll
        for (int o = 32; o > 0; o >>= 1) {
            sL += __shfl_xor(sL, o, 64);
            sD += __shfl_xor(sD, o, 64);
        }
        if (lane == 0) { red[w] = sL; red[2 + w] = sD; }
        if (t == 0)   { spx[0] = l0; spx[3] = d0; }
        if (t == 1)   { spx[1] = l1; spx[4] = d1; }
        if (t == 103) { spx[2] = lN; spx[5] = dN; }
        __syncthreads();
        if (t == 0) {
            float SL = red[0] + red[1], SD = red[2] + red[3];
            float Lv  = 4.f * zq * trapz_ext(SL, spx[0], spx[1], spx[2]) / PI_F;
            float dLv = trapz_ext(SD, spx[3], spx[4], spx[5]) / PI_F;
            ws[16 + i] = dLv;
            ws[16 + 2 * NG + i] = Lv;
        }
    } else {
        float sc = 0.f, sd = 0.f, c0 = 0.f, c1v = 0.f, cN = 0.f,
              q0 = 0.f, qN = 0.f;
#pragma unroll
        for (int k = 0; k < 8; ++k) {
            if (k < 7 || t < 104) {
                int j = t + 128 * k;
                float y = fmaf((float)j, DYF, 0.001f);
                float u = 1.f - y * y;
                float vc = point_Vc(c, U, y, u);
                float y2 = fmaf((float)j, DY2F, 0.001f);
                float vd = point_Vd(c, U, y2);
                sc += vc; sd += vd;
                if (k == 0) {
                    if (t == 0) { c0 = vc; q0 = vd; }
                    if (t == 1) { c1v = vc; }
                }
                if (k == 7 && t == 103) { cN = vc; qN = vd; }
            }
        }
#pragma unroll
        for (int o = 32; o > 0; o >>= 1) {
            sc += __shfl_xor(sc, o, 64);
            sd += __shfl_xor(sd, o, 64);
        }
        if (lane == 0) { red[w] = sc; red[2 + w] = sd; }
        if (t == 0)   { spx[0] = c0; spx[3] = q0; }
        if (t == 1)   { spx[1] = c1v; }
        if (t == 103) { spx[2] = cN; spx[4] = qN; }
        __syncthreads();
        if (t == 0) {
            float Sc = red[0] + red[1], Sd = red[2] + red[3];
            float Vc = c.coef * PI_F * 4.f * trapz_ext(Sc, spx[0], spx[1], spx[2]) * frcp(zq);
            float Vd = c.coef * PI_F * 2.f * (1.f - zq) * trapz_d(Sd, spx[3], spx[4]);
            ws[16 + NG + i] = Vc - Vd;
        }
    }
}

// ---------------------------------------------------------------------------
// Kernel B: per-element output.  64 blocks x 64 threads (1 wave), 64
// elements per block.  Each block: (1) redundant scan of the 8 KB tables
// (L2-resident) for the dL and V sign crossings -> bound, L_crit; (2) per
// thread: validity gate, Hermite inversion of (L,dL) -> zs; if zs >= ZT,
// 4-point cubic Lagrange interp of the V table (error ~C h^4/z^5 < 1e-2,
// below table noise); else push to an LDS list; (3) wave-wide exact V
// quadrature for the listed (rare, small-zs) elements.
// ---------------------------------------------------------------------------
__global__ __launch_bounds__(64) void elem_out_kernel(
        const float* Ls, const float* a, const float* b, const float* lc,
        const float* ws, float* out, int B) {
    __shared__ int sdl, sv, nlist;
    __shared__ float sLcrit;
    __shared__ int lidx[64];
    __shared__ float lzs[64];
    const float* dLbuf = ws + 16;
    const float* Vbuf  = ws + 16 + NG;
    const float* Lbuf  = ws + 16 + 2 * NG;
    int t = threadIdx.x;

    // --- phase 1: table scan (redundant per block) ---
    if (t == 0) { sdl = NG; sv = NG; nlist = 0; }
    __syncthreads();
#pragma unroll
    for (int r = 0; r < NG / 64; ++r) {
        int i = t + 64 * r;
        float dcur = dLbuf[i];
        float dprev = (i > 0) ? dLbuf[i - 1] : 1.f;     // dL(lo) >= 0 invariant
        if (dcur < 0.f && dprev >= 0.f) atomicMin(&sdl, i);
        float vcur = Vbuf[i];
        float vprev = (i > 0) ? Vbuf[i - 1] : -1.f;     // V(lo) <= 0 invariant
        if (vcur > 0.f && vprev <= 0.f) atomicMin(&sv, i);
    }
    __syncthreads();
    int bound = sdl;
    int iv = sv;
    if (t == 0) {
        float Lcrit;
        if (bound < 2) {
            Lcrit = -1.f;                       // degenerate: everything invalid
        } else if (iv >= NG || iv >= bound) {
            Lcrit = Lbuf[bound - 1];            // no crossing in range -> ~L_max
        } else if (iv == 0) {
            float z0 = 0.001f + 0.5f * HG;
            Lcrit = Lbuf[0] * 0.001f * frcp(z0);
        } else {
            float zhi = fmaf((float)iv + 0.5f, HG, 0.001f);
            float zlo = zhi - HG;
            float vhi = Vbuf[iv], vlo = Vbuf[iv - 1];
            float zc = zlo - vlo * (zhi - zlo) * frcp(fmaxf(vhi - vlo, 1e-30f));
            zc = fminf(fmaxf(zc, zlo), zhi);
            float tt = (zc - 0.001f) * frcp(HG) - 0.5f;
            int i0 = (int)tt;
            i0 = max(0, min(i0, bound - 2));
            float frac = fminf(fmaxf(tt - (float)i0, 0.f), 1.f);
            Lcrit = Lbuf[i0] + frac * (Lbuf[i0 + 1] - Lbuf[i0]);
        }
        sLcrit = Lcrit;
    }
    __syncthreads();
    float L_crit = sLcrit;

    // --- phase 2: per-thread inversion + V interp / list push ---
    int e = blockIdx.x * 64 + t;
    if (e < B) {
        float Lq = Ls[e];
        if (!(Lq < L_crit) || bound < 2) {
            out[e] = 0.f;                       // invalid row: exact 0
        } else {
            // largest lo in [0, bound) with L[lo] < Lq
            int lo = -1, hi = bound - 1;
            while (hi > lo) {
                int mid = (lo + hi + 1) >> 1;
                if (Lbuf[mid] < Lq) lo = mid; else hi = mid - 1;
            }
            float zs;
            if (lo < 0) {
                float z0 = 0.001f + 0.5f * HG;
                zs = z0 * Lq * frcp(fmaxf(Lbuf[0], 1e-20f));
            } else {
                int seg = min(lo, bound - 2);
                float zl = fmaf((float)seg + 0.5f, HG, 0.001f);
                float Ll = Lbuf[seg],  Lh = Lbuf[seg + 1];
                float dl = dLbuf[seg] * HG, dh = dLbuf[seg + 1] * HG;
                float s = fminf(fmaxf((Lq - Ll) * frcp(fmaxf(Lh - Ll, 1e-20f)), 0.f), 1.f);
#pragma unroll
                for (int it = 0; it < 2; ++it) {
                    float s2 = s * s, s3 = s2 * s;
                    float H  = (2.f*s3 - 3.f*s2 + 1.f) * Ll + (s3 - 2.f*s2 + s) * dl
                             + (-2.f*s3 + 3.f*s2) * Lh + (s3 - s2) * dh;
                    float Hp = (6.f*s2 - 6.f*s) * (Ll - Lh)
                             + (3.f*s2 - 4.f*s + 1.f) * dl + (3.f*s2 - 2.f*s) * dh;
                    float step = (H - Lq) * frcp(Hp);
                    if (fabsf(Hp) > 1e-20f) s = fminf(fmaxf(s - step, 0.f), 1.f);
                }
                zs = fmaf(s, HG, zl);
            }
            zs = fminf(fmaxf(zs, 1e-4f), 0.9995f);

            if (zs >= ZT) {
                // 4-point cubic Lagrange interp of V(z) at zs
                float tt = (zs - 0.001f) * frcp(HG) - 0.5f;
                int i0 = (int)tt;
                i0 = max(1, min(i0, NG - 3));
                float s = tt - (float)i0;
                float vm = Vbuf[i0 - 1], v0 = Vbuf[i0], v1 = Vbuf[i0 + 1], v2 = Vbuf[i0 + 2];
                float wm = -s * (s - 1.f) * (s - 2.f) * (1.f / 6.f);
                float w0 = (s + 1.f) * (s - 1.f) * (s - 2.f) * 0.5f;
                float w1 = -(s + 1.f) * s * (s - 2.f) * 0.5f;
                float w2 = (s + 1.f) * s * (s - 1.f) * (1.f / 6.f);
                out[e] = wm * vm + w0 * v0 + w1 * v1 + w2 * v2;
            } else {
                int slot = atomicAdd(&nlist, 1);
                lidx[slot] = e;
                lzs[slot] = zs;
            }
        }
    }
    __syncthreads();

    // --- phase 3: exact V quadrature for listed elements (wave-wide) ---
    int n = nlist;
    if (n > 0) {
        Co c = make_co(a, b, lc);
        for (int q = 0; q < n; ++q) {
            float zq = lzs[q];
            Uni U = make_uni(c, zq);
            float V = wave_V(c, U, t);
            if (t == 0) out[lidx[q]] = V;
        }
    }
}

// ---------------------------------------------------------------------------
extern "C" void kernel_launch(void* const* d_in, const int* in_sizes, int n_in,
                              void* d_out, int out_size, void* d_ws, size_t ws_size,
                              hipStream_t stream) {
    const float* Ls = (const float*)d_in[0];
    const float* a  = (const float*)d_in[1];
    const float* b  = (const float*)d_in[2];
    const float* lc = (const float*)d_in[3];
    float* out = (float*)d_out;
    float* ws  = (float*)d_ws;
    int B = in_sizes[0];

    grid_eval_kernel<<<2 * NG, 128, 0, stream>>>(a, b, lc, ws);
    int blocksB = (B + 63) / 64;
    elem_out_kernel<<<blocksB, 64, 0, stream>>>(Ls, a, b, lc, ws, out, B);
}

// Round 19
// 84.669 us; speedup vs baseline: 1.2747x; 1.2747x over previous
//
#include <hip/hip_runtime.h>
#include <math.h>

#define MQ 1000
#define PI_F 3.14159265358979323846f
#define EPSF 1e-12f
#define DYF  ((float)(0.998/999.0))   // main y-grid step
#define DY2F ((float)(0.999/999.0))   // disconnected y2-grid step (= 0.001)
#define NG   2048                     // scan-grid points per function
#define HG   (0.998f / (float)NG)     // scan-grid step
#define ZT   0.006f                   // V-interp threshold (err ~0.4 at 0.006, ~3e-5 at 0.02)

// fast HW approx ops (v_rcp_f32 / v_rsq_f32 / v_sqrt_f32, ~1 ulp)
__device__ __forceinline__ float frcp(float x)  { return __builtin_amdgcn_rcpf(x); }
__device__ __forceinline__ float frsq(float x)  { return __builtin_amdgcn_rsqf(x); }
__device__ __forceinline__ float fsqrt(float x) { return __builtin_amdgcn_sqrtf(x); }

// ws layout: [0]=L_crit [1]=bound (float)
//            [16 .. 16+NG)        = dL grid
//            [16+NG .. 16+2NG)    = V grid
//            [16+2NG .. 16+3NG)   = L grid (monotone for z < zs_max)
//            grid z_i = 0.001 + (i+0.5)*HG

// ---------------------------------------------------------------------------
struct Co {
    float q1, q2, q3, q4, cf4;
    float e1, e2, e3, e4;
    float b0, b1, p3;
    float coef;
};

__device__ __forceinline__ Co make_co(const float* a, const float* b, const float* lc) {
    Co c;
    float a0 = a[0], a1 = a[1];
    float cf1 = -8.f * a0 / 3.f;
    float cf2 = -2.f * (2.f * a1 + a0 * a0);
    float cf3 = -8.f * a0 * a1;
    c.cf4 = -4.f * a1 * a1;
    c.q1 = -cf1; c.q2 = -cf2; c.q3 = -cf3; c.q4 = cf1 + cf2 + cf3 - 1.f;
    c.e1 = 2.f * a0;
    c.e2 = 2.f * a1 + a0 * a0;
    c.e3 = 2.f * a0 * a1;
    c.e4 = a1 * a1;
    c.b0 = b[0]; c.b1 = b[1];
    c.p3 = a0 + a1 - b[0] - b[1];
    c.coef = expf(lc[0]);
    return c;
}

struct Uni { float zs, fs, rfs, A4; };

__device__ __forceinline__ Uni make_uni(const Co& c, float zs) {
    Uni U; U.zs = zs;
    float z = zs;
    float lg = __logf(z);
    float t4 = c.q4 + c.cf4 * lg;
    float fz = 1.f + z * (c.q1 + z * (c.q2 + z * (c.q3 + z * t4)));
    float s  = 1.f + z * (c.e1 + z * (c.e2 + z * (c.e3 + z * c.e4)));
    U.fs = fz;
    U.rfs = frcp(fz);
    float dfs = 4.f * (fz - s) * frcp(z);
    U.A4 = zs * dfs * U.rfs - 2.f;     // (zs dfs/fs + 2) - 4
    return U;
}

__device__ __forceinline__ void point_LdL(const Co& c, const Uni& U,
                                          float y, float u,
                                          float& iL, float& iD) {
    float u2  = u * u;
    float ru2 = frcp(u2);
    float ru4 = ru2 * ru2;
    float z  = U.zs * u;
    float z2 = z * z, z4 = z2 * z2;
    float lg = __logf(z);
    float t4 = c.q4 + c.cf4 * lg;
    float fz = 1.f + z * (c.q1 + z * (c.q2 + z * (c.q3 + z * t4)));
    float s  = 1.f + z * (c.e1 + z * (c.e2 + z * (c.e3 + z * c.e4)));
    float P  = 1.f + z * (c.b0 + z * (c.b1 + z * c.p3));
    float dP = c.b0 + z * (2.f * c.b1 + z * (3.f * c.p3));
    float D  = 1.f - z4;
    float rsqD = frsq(D);
    float rcpD = rsqD * rsqD;
    float rcpP = frcp(P);
    float zdgg = 2.f * z * dP * rcpP + 4.f * z4 * rcpD;   // z dg / g
    float F4 = fz * U.rfs * ru4;                          // r4 * f/fs
    float S4 = s  * U.rfs * ru4;
    float den = fmaxf(F4 - 1.f, EPSF);
    float rs  = frsq(den);
    float sqg = P * rsqD;
    float t1  = sqg * rs;
    iL = t1 * y;
    float t = F4 * (U.A4 + zdgg) + 4.f * S4 - 2.f - zdgg;
    float rs2 = rs * rs;
    iD = t * (2.f * y) * (t1 * rs2);                      // sqrt(1-z/zs) = y
}

__device__ __forceinline__ float point_Vc(const Co& c, const Uni& U,
                                          float y, float u) {
    float u2  = u * u;
    float u4  = u2 * u2;
    float ru2 = frcp(u2);
    float z  = U.zs * u;
    float z2 = z * z, z4 = z2 * z2;
    float lg = __logf(z);
    float t4 = c.q4 + c.cf4 * lg;
    float fz = 1.f + z * (c.q1 + z * (c.q2 + z * (c.q3 + z * t4)));
    float P  = 1.f + z * (c.b0 + z * (c.b1 + z * c.p3));
    float D  = 1.f - z4;
    float rsqD = frsq(D);
    float rcpD = rsqD * rsqD;
    float fg = fz * P * P * rcpD;
    float sqfg = fsqrt(fmaxf(fg, EPSF));
    float rfz = frcp(fz);
    float arg = fmaxf(1.f - u4 * U.fs * rfz, EPSF);
    float t = frsq(arg) - 1.f;
    return sqfg * ru2 * t * y;
}

__device__ __forceinline__ float point_Vd(const Co& c, const Uni& U, float y2) {
    float z  = 1.f - (1.f - U.zs) * y2;
    float z2 = z * z, z4 = z2 * z2;
    float lg = __logf(z);
    float t4 = c.q4 + c.cf4 * lg;
    float fz = 1.f + z * (c.q1 + z * (c.q2 + z * (c.q3 + z * t4)));
    float P  = 1.f + z * (c.b0 + z * (c.b1 + z * c.p3));
    float D  = 1.f - z4;
    float rsqD = frsq(D);
    float fg = fz * P * P * (rsqD * rsqD);
    float sq = fsqrt(fmaxf(fg, EPSF));
    float rz = frcp(z);
    return sq * rz * rz;
}

__device__ __forceinline__ float trapz_ext(float S, float i0, float i1, float iN) {
    float slope = (i1 - i0) * frcp(DYF);
    float v0 = i0 - slope * 0.001f;
    float yLast = 0.001f + 999.f * DYF;
    return DYF * (S - 0.5f * (i0 + iN))
         + 0.5f * (v0 + i0) * 0.001f
         + 0.5f * iN * (1.f - yLast);
}

__device__ __forceinline__ float trapz_d(float S, float q0, float qN) {
    return 0.5f * (1.f + q0) * 0.001f + DY2F * (S - 0.5f * (q0 + qN));
}

// ---------------------------------------------------------------------------
// Kernel A: grid evaluation, 2 waves (128 threads) per grid point.
// Block i<NG: L and dL at z_i; block i>=NG: V at z_{i-NG}.
// j = t + 128k; j=0,1 -> t=0,1 (k=0); j=999 -> t=103 (k=7).
// ---------------------------------------------------------------------------
__global__ __launch_bounds__(128) void grid_eval_kernel(
        const float* a, const float* b, const float* lc, float* ws) {
    __shared__ float red[4];
    __shared__ float spx[8];
    int bid = blockIdx.x;
    int t = threadIdx.x, lane = t & 63, w = t >> 6;
    Co c = make_co(a, b, lc);
    int i = (bid < NG) ? bid : bid - NG;
    float zq = fmaf((float)i + 0.5f, HG, 0.001f);
    Uni U = make_uni(c, zq);

    if (bid < NG) {
        float sL = 0.f, sD = 0.f, l0 = 0.f, d0 = 0.f, l1 = 0.f, d1 = 0.f,
              lN = 0.f, dN = 0.f;
#pragma unroll
        for (int k = 0; k < 8; ++k) {
            if (k < 7 || t < 104) {
                int j = t + 128 * k;
                float y = fmaf((float)j, DYF, 0.001f);
                float u = 1.f - y * y;
                float iL, iD;
                point_LdL(c, U, y, u, iL, iD);
                sL += iL; sD += iD;
                if (k == 0) {
                    if (t == 0) { l0 = iL; d0 = iD; }
                    if (t == 1) { l1 = iL; d1 = iD; }
                }
                if (k == 7 && t == 103) { lN = iL; dN = iD; }
            }
        }
#pragma unroll
        for (int o = 32; o > 0; o >>= 1) {
            sL += __shfl_xor(sL, o, 64);
            sD += __shfl_xor(sD, o, 64);
        }
        if (lane == 0) { red[w] = sL; red[2 + w] = sD; }
        if (t == 0)   { spx[0] = l0; spx[3] = d0; }
        if (t == 1)   { spx[1] = l1; spx[4] = d1; }
        if (t == 103) { spx[2] = lN; spx[5] = dN; }
        __syncthreads();
        if (t == 0) {
            float SL = red[0] + red[1], SD = red[2] + red[3];
            float Lv  = 4.f * zq * trapz_ext(SL, spx[0], spx[1], spx[2]) / PI_F;
            float dLv = trapz_ext(SD, spx[3], spx[4], spx[5]) / PI_F;
            ws[16 + i] = dLv;
            ws[16 + 2 * NG + i] = Lv;
        }
    } else {
        float sc = 0.f, sd = 0.f, c0 = 0.f, c1v = 0.f, cN = 0.f,
              q0 = 0.f, qN = 0.f;
#pragma unroll
        for (int k = 0; k < 8; ++k) {
            if (k < 7 || t < 104) {
                int j = t + 128 * k;
                float y = fmaf((float)j, DYF, 0.001f);
                float u = 1.f - y * y;
                float vc = point_Vc(c, U, y, u);
                float y2 = fmaf((float)j, DY2F, 0.001f);
                float vd = point_Vd(c, U, y2);
                sc += vc; sd += vd;
                if (k == 0) {
                    if (t == 0) { c0 = vc; q0 = vd; }
                    if (t == 1) { c1v = vc; }
                }
                if (k == 7 && t == 103) { cN = vc; qN = vd; }
            }
        }
#pragma unroll
        for (int o = 32; o > 0; o >>= 1) {
            sc += __shfl_xor(sc, o, 64);
            sd += __shfl_xor(sd, o, 64);
        }
        if (lane == 0) { red[w] = sc; red[2 + w] = sd; }
        if (t == 0)   { spx[0] = c0; spx[3] = q0; }
        if (t == 1)   { spx[1] = c1v; }
        if (t == 103) { spx[2] = cN; spx[4] = qN; }
        __syncthreads();
        if (t == 0) {
            float Sc = red[0] + red[1], Sd = red[2] + red[3];
            float Vc = c.coef * PI_F * 4.f * trapz_ext(Sc, spx[0], spx[1], spx[2]) * frcp(zq);
            float Vd = c.coef * PI_F * 2.f * (1.f - zq) * trapz_d(Sd, spx[3], spx[4]);
            ws[16 + NG + i] = Vc - Vd;
        }
    }
}

// ---------------------------------------------------------------------------
// Kernel B: 1-block table scan (R16/R17).
// ---------------------------------------------------------------------------
__global__ __launch_bounds__(256) void scan_kernel(float* ws) {
    __shared__ int sdl, sv;
    const float* dLbuf = ws + 16;
    const float* Vbuf  = ws + 16 + NG;
    const float* Lbuf  = ws + 16 + 2 * NG;
    int t = threadIdx.x;
    if (t == 0) { sdl = NG; sv = NG; }
    __syncthreads();
#pragma unroll
    for (int r = 0; r < NG / 256; ++r) {
        int i = t + 256 * r;
        float dcur = dLbuf[i];
        float dprev = (i > 0) ? dLbuf[i - 1] : 1.f;     // dL(lo) >= 0 invariant
        if (dcur < 0.f && dprev >= 0.f) atomicMin(&sdl, i);
        float vcur = Vbuf[i];
        float vprev = (i > 0) ? Vbuf[i - 1] : -1.f;     // V(lo) <= 0 invariant
        if (vcur > 0.f && vprev <= 0.f) atomicMin(&sv, i);
    }
    __syncthreads();
    if (t == 0) {
        int bound = sdl, iv = sv;
        float Lcrit;
        if (bound < 2) {
            Lcrit = -1.f;                       // degenerate: everything invalid
        } else if (iv >= NG || iv >= bound) {
            Lcrit = Lbuf[bound - 1];            // no crossing in range -> ~L_max
        } else if (iv == 0) {
            float z0 = 0.001f + 0.5f * HG;
            Lcrit = Lbuf[0] * 0.001f * frcp(z0);   // crossing at lo endpoint
        } else {
            float zhi = fmaf((float)iv + 0.5f, HG, 0.001f);
            float zlo = zhi - HG;
            float vhi = Vbuf[iv], vlo = Vbuf[iv - 1];
            float zc = zlo - vlo * (zhi - zlo) * frcp(fmaxf(vhi - vlo, 1e-30f));
            zc = fminf(fmaxf(zc, zlo), zhi);
            float tt = (zc - 0.001f) * frcp(HG) - 0.5f;
            int i0 = (int)tt;
            i0 = max(0, min(i0, bound - 2));
            float frac = fminf(fmaxf(tt - (float)i0, 0.f), 1.f);
            Lcrit = Lbuf[i0] + frac * (Lbuf[i0 + 1] - Lbuf[i0]);
        }
        ws[0] = Lcrit;
        ws[1] = (float)bound;
    }
}

// ---------------------------------------------------------------------------
// Kernel C: per-element (R17 structure: 1 block of 128 = 2 waves per
// element, 4096 blocks for TLP).  Hermite inversion of (L, dL) -> zs.
// R19 fast path: for zs >= ZT, 4-point cubic Lagrange interp of the V
// table (err ~(24C/z^5)h^4/24, C~1.6 calibrated from ref absmax 1.6e4 at
// zs~1e-4: ~0.4 at z=0.006, ~3e-5 at z=0.02 — << threshold 318) and exit;
// only the rare zs < ZT elements (~0.3%) run the exact 2-wave quadrature.
// R18 failed by shrinking to 64 single-wave blocks (latency-bound, 40 us);
// here the fast path keeps full block-level parallelism.
// ---------------------------------------------------------------------------
__global__ __launch_bounds__(128) void elem_v_kernel(
        const float* Ls, const float* a, const float* b, const float* lc,
        const float* ws, float* out, int B) {
    __shared__ float red[4];
    __shared__ float spx[8];
    int wid = blockIdx.x;
    int t = threadIdx.x, lane = t & 63, w = t >> 6;
    if (wid >= B) return;

    float L_crit = ws[0];
    int bound = (int)ws[1];
    float Lq = Ls[wid];
    if (!(Lq < L_crit) || bound < 2) {   // invalid row: exact 0
        if (t == 0) out[wid] = 0.f;
        return;
    }

    const float* dLbuf = ws + 16;
    const float* Vbuf  = ws + 16 + NG;
    const float* Lbuf  = ws + 16 + 2 * NG;
    // largest lo in [0, bound) with L[lo] < Lq (block-uniform, redundant)
    int lo = -1, hi = bound - 1;
    while (hi > lo) {
        int mid = (lo + hi + 1) >> 1;
        if (Lbuf[mid] < Lq) lo = mid; else hi = mid - 1;
    }
    float zs;
    if (lo < 0) {
        // below first sample: L ~ linear through origin (rel err ~0.05*zs)
        float z0 = 0.001f + 0.5f * HG;
        zs = z0 * Lq * frcp(fmaxf(Lbuf[0], 1e-20f));
    } else {
        int seg = min(lo, bound - 2);
        float zl = fmaf((float)seg + 0.5f, HG, 0.001f);
        float Ll = Lbuf[seg],  Lh = Lbuf[seg + 1];
        float dl = dLbuf[seg] * HG, dh = dLbuf[seg + 1] * HG;  // d/ds scale
        float s = fminf(fmaxf((Lq - Ll) * frcp(fmaxf(Lh - Ll, 1e-20f)), 0.f), 1.f);
#pragma unroll
        for (int it = 0; it < 2; ++it) {
            float s2 = s * s, s3 = s2 * s;
            float H  = (2.f*s3 - 3.f*s2 + 1.f) * Ll + (s3 - 2.f*s2 + s) * dl
                     + (-2.f*s3 + 3.f*s2) * Lh + (s3 - s2) * dh;
            float Hp = (6.f*s2 - 6.f*s) * (Ll - Lh)
                     + (3.f*s2 - 4.f*s + 1.f) * dl + (3.f*s2 - 2.f*s) * dh;
            float step = (H - Lq) * frcp(Hp);
            if (fabsf(Hp) > 1e-20f) s = fminf(fmaxf(s - step, 0.f), 1.f);
        }
        zs = fmaf(s, HG, zl);
    }
    zs = fminf(fmaxf(zs, 1e-4f), 0.9995f);

    // fast path: cubic Lagrange interp of the V table (block-uniform branch)
    if (zs >= ZT) {
        if (t == 0) {
            float tt = (zs - 0.001f) * frcp(HG) - 0.5f;
            int i0 = (int)tt;
            i0 = max(1, min(i0, NG - 3));
            float s = tt - (float)i0;
            float vm = Vbuf[i0 - 1], v0 = Vbuf[i0], v1 = Vbuf[i0 + 1], v2 = Vbuf[i0 + 2];
            float wm = -s * (s - 1.f) * (s - 2.f) * (1.f / 6.f);
            float w0 = (s + 1.f) * (s - 1.f) * (s - 2.f) * 0.5f;
            float w1 = -(s + 1.f) * s * (s - 2.f) * 0.5f;
            float w2 = (s + 1.f) * s * (s - 1.f) * (1.f / 6.f);
            out[wid] = wm * vm + w0 * v0 + w1 * v1 + w2 * v2;
        }
        return;
    }

    // slow path (~0.3% of elements): exact V quadrature (8 pts/lane x 2 waves)
    Co c = make_co(a, b, lc);
    Uni U = make_uni(c, zs);
    float sc = 0.f, sd = 0.f, c0 = 0.f, c1v = 0.f, cN = 0.f, q0 = 0.f, qN = 0.f;
#pragma unroll
    for (int k = 0; k < 8; ++k) {
        if (k < 7 || t < 104) {
            int j = t + 128 * k;
            float y = fmaf((float)j, DYF, 0.001f);
            float u = 1.f - y * y;
            float vc = point_Vc(c, U, y, u);
            float y2 = fmaf((float)j, DY2F, 0.001f);
            float vd = point_Vd(c, U, y2);
            sc += vc; sd += vd;
            if (k == 0) {
                if (t == 0) { c0 = vc; q0 = vd; }
                if (t == 1) { c1v = vc; }
            }
            if (k == 7 && t == 103) { cN = vc; qN = vd; }
        }
    }
#pragma unroll
    for (int o = 32; o > 0; o >>= 1) {
        sc += __shfl_xor(sc, o, 64);
        sd += __shfl_xor(sd, o, 64);
    }
    if (lane == 0) { red[w] = sc; red[2 + w] = sd; }
    if (t == 0)   { spx[0] = c0; spx[3] = q0; }
    if (t == 1)   { spx[1] = c1v; }
    if (t == 103) { spx[2] = cN; spx[4] = qN; }
    __syncthreads();
    if (t == 0) {
        float Sc = red[0] + red[1], Sd = red[2] + red[3];
        float Vc = c.coef * PI_F * 4.f * trapz_ext(Sc, spx[0], spx[1], spx[2]) * frcp(zs);
        float Vd = c.coef * PI_F * 2.f * (1.f - zs) * trapz_d(Sd, spx[3], spx[4]);
        out[wid] = Vc - Vd;
    }
}

// ---------------------------------------------------------------------------
extern "C" void kernel_launch(void* const* d_in, const int* in_sizes, int n_in,
                              void* d_out, int out_size, void* d_ws, size_t ws_size,
                              hipStream_t stream) {
    const float* Ls = (const float*)d_in[0];
    const float* a  = (const float*)d_in[1];
    const float* b  = (const float*)d_in[2];
    const float* lc = (const float*)d_in[3];
    float* out = (float*)d_out;
    float* ws  = (float*)d_ws;
    int B = in_sizes[0];

    grid_eval_kernel<<<2 * NG, 128, 0, stream>>>(a, b, lc, ws);
    scan_kernel<<<1, 256, 0, stream>>>(ws);
    elem_v_kernel<<<B, 128, 0, stream>>>(Ls, a, b, lc, ws, out, B);
}

// Round 20
// 78.347 us; speedup vs baseline: 1.3776x; 1.0807x over previous
//
#include <hip/hip_runtime.h>
#include <math.h>

#define MQ 1000
#define PI_F 3.14159265358979323846f
#define EPSF 1e-12f
#define DYF  ((float)(0.998/999.0))   // main y-grid step
#define DY2F ((float)(0.999/999.0))   // disconnected y2-grid step (= 0.001)
#define NG   1024                     // scan-grid points (h^4 interp errs still << threshold)
#define HG   (0.998f / (float)NG)     // scan-grid step
#define ZT   0.006f                   // V-interp threshold; below -> exact quadrature

// fast HW approx ops (v_rcp_f32 / v_rsq_f32 / v_sqrt_f32, ~1 ulp)
__device__ __forceinline__ float frcp(float x)  { return __builtin_amdgcn_rcpf(x); }
__device__ __forceinline__ float frsq(float x)  { return __builtin_amdgcn_rsqf(x); }
__device__ __forceinline__ float fsqrt(float x) { return __builtin_amdgcn_sqrtf(x); }

// ws layout: [0]=L_crit [1]=bound (float)
//            [16 .. 16+NG)        = dL grid
//            [16+NG .. 16+2NG)    = V grid
//            [16+2NG .. 16+3NG)   = L grid (monotone for z < zs_max)
//            grid z_i = 0.001 + (i+0.5)*HG

// ---------------------------------------------------------------------------
struct Co {
    float q1, q2, q3, q4, cf4;
    float e1, e2, e3, e4;
    float b0, b1, p3;
    float coef;
};

__device__ __forceinline__ Co make_co(const float* a, const float* b, const float* lc) {
    Co c;
    float a0 = a[0], a1 = a[1];
    float cf1 = -8.f * a0 / 3.f;
    float cf2 = -2.f * (2.f * a1 + a0 * a0);
    float cf3 = -8.f * a0 * a1;
    c.cf4 = -4.f * a1 * a1;
    c.q1 = -cf1; c.q2 = -cf2; c.q3 = -cf3; c.q4 = cf1 + cf2 + cf3 - 1.f;
    c.e1 = 2.f * a0;
    c.e2 = 2.f * a1 + a0 * a0;
    c.e3 = 2.f * a0 * a1;
    c.e4 = a1 * a1;
    c.b0 = b[0]; c.b1 = b[1];
    c.p3 = a0 + a1 - b[0] - b[1];
    c.coef = expf(lc[0]);
    return c;
}

struct Uni { float zs, fs, rfs, A4; };

__device__ __forceinline__ Uni make_uni(const Co& c, float zs) {
    Uni U; U.zs = zs;
    float z = zs;
    float lg = __logf(z);
    float t4 = c.q4 + c.cf4 * lg;
    float fz = 1.f + z * (c.q1 + z * (c.q2 + z * (c.q3 + z * t4)));
    float s  = 1.f + z * (c.e1 + z * (c.e2 + z * (c.e3 + z * c.e4)));
    U.fs = fz;
    U.rfs = frcp(fz);
    float dfs = 4.f * (fz - s) * frcp(z);
    U.A4 = zs * dfs * U.rfs - 2.f;     // (zs dfs/fs + 2) - 4
    return U;
}

// merged per-point eval: iL, iD (L and dL integrands) AND vc (connected-V
// integrand) at the same z = zs*u — shares z, log, f(z), P(z), D, rsqD.
__device__ __forceinline__ void point_all(const Co& c, const Uni& U,
                                          float y, float u,
                                          float& iL, float& iD, float& vc) {
    float u2  = u * u;
    float u4  = u2 * u2;
    float ru2 = frcp(u2);
    float ru4 = ru2 * ru2;
    float z  = U.zs * u;
    float z2 = z * z, z4 = z2 * z2;
    float lg = __logf(z);
    float t4 = c.q4 + c.cf4 * lg;
    float fz = 1.f + z * (c.q1 + z * (c.q2 + z * (c.q3 + z * t4)));
    float s  = 1.f + z * (c.e1 + z * (c.e2 + z * (c.e3 + z * c.e4)));
    float P  = 1.f + z * (c.b0 + z * (c.b1 + z * c.p3));
    float dP = c.b0 + z * (2.f * c.b1 + z * (3.f * c.p3));
    float D  = 1.f - z4;
    float rsqD = frsq(D);
    float rcpD = rsqD * rsqD;
    float rcpP = frcp(P);
    float zdgg = 2.f * z * dP * rcpP + 4.f * z4 * rcpD;   // z dg / g
    float F4 = fz * U.rfs * ru4;                          // r4 * f/fs
    float S4 = s  * U.rfs * ru4;
    float den = fmaxf(F4 - 1.f, EPSF);
    float rs  = frsq(den);
    float sqg = P * rsqD;                                 // sqrt(g)
    float t1  = sqg * rs;
    iL = t1 * y;
    float tnum = F4 * (U.A4 + zdgg) + 4.f * S4 - 2.f - zdgg;
    float rs2 = rs * rs;
    iD = tnum * (2.f * y) * (t1 * rs2);                   // sqrt(1-z/zs) = y
    // connected-V integrand (reuses fz, P, rcpD)
    float fg = fz * P * P * rcpD;
    float sqfg = fsqrt(fmaxf(fg, EPSF));
    float rfz = frcp(fz);
    float arg = fmaxf(1.f - u4 * U.fs * rfz, EPSF);       // 1 - w^2/fof
    float tv = frsq(arg) - 1.f;
    vc = sqfg * ru2 * tv * y;
}

__device__ __forceinline__ float point_Vc(const Co& c, const Uni& U,
                                          float y, float u) {
    float u2  = u * u;
    float u4  = u2 * u2;
    float ru2 = frcp(u2);
    float z  = U.zs * u;
    float z2 = z * z, z4 = z2 * z2;
    float lg = __logf(z);
    float t4 = c.q4 + c.cf4 * lg;
    float fz = 1.f + z * (c.q1 + z * (c.q2 + z * (c.q3 + z * t4)));
    float P  = 1.f + z * (c.b0 + z * (c.b1 + z * c.p3));
    float D  = 1.f - z4;
    float rsqD = frsq(D);
    float rcpD = rsqD * rsqD;
    float fg = fz * P * P * rcpD;
    float sqfg = fsqrt(fmaxf(fg, EPSF));
    float rfz = frcp(fz);
    float arg = fmaxf(1.f - u4 * U.fs * rfz, EPSF);
    float t = frsq(arg) - 1.f;
    return sqfg * ru2 * t * y;
}

__device__ __forceinline__ float point_Vd(const Co& c, const Uni& U, float y2) {
    float z  = 1.f - (1.f - U.zs) * y2;
    float z2 = z * z, z4 = z2 * z2;
    float lg = __logf(z);
    float t4 = c.q4 + c.cf4 * lg;
    float fz = 1.f + z * (c.q1 + z * (c.q2 + z * (c.q3 + z * t4)));
    float P  = 1.f + z * (c.b0 + z * (c.b1 + z * c.p3));
    float D  = 1.f - z4;
    float rsqD = frsq(D);
    float fg = fz * P * P * (rsqD * rsqD);
    float sq = fsqrt(fmaxf(fg, EPSF));
    float rz = frcp(z);
    return sq * rz * rz;
}

__device__ __forceinline__ float trapz_ext(float S, float i0, float i1, float iN) {
    float slope = (i1 - i0) * frcp(DYF);
    float v0 = i0 - slope * 0.001f;
    float yLast = 0.001f + 999.f * DYF;
    return DYF * (S - 0.5f * (i0 + iN))
         + 0.5f * (v0 + i0) * 0.001f
         + 0.5f * iN * (1.f - yLast);
}

__device__ __forceinline__ float trapz_d(float S, float q0, float qN) {
    return 0.5f * (1.f + q0) * 0.001f + DY2F * (S - 0.5f * (q0 + qN));
}

// ---------------------------------------------------------------------------
// Kernel A: merged grid evaluation — ONE block (128 threads, 2 waves) per
// grid point computes L, dL AND V at z_i.  The L/dL and connected-V
// integrands share z, log(z), f(z), P(z) per quadrature point (3 logs/pt
// across R19's two passes -> 2), and block count halves.
// j = t + 128k; j=0,1 -> t=0,1 (k=0); j=999 -> t=103 (k=7).
// ---------------------------------------------------------------------------
__global__ __launch_bounds__(128) void grid_eval_kernel(
        const float* a, const float* b, const float* lc, float* ws) {
    __shared__ float red[8];    // [4 sums][2 waves]
    __shared__ float spx[12];
    int i = blockIdx.x;
    int t = threadIdx.x, lane = t & 63, w = t >> 6;
    Co c = make_co(a, b, lc);
    float zq = fmaf((float)i + 0.5f, HG, 0.001f);
    Uni U = make_uni(c, zq);

    float sL = 0.f, sD = 0.f, sc = 0.f, sd = 0.f;
    float l0 = 0.f, l1 = 0.f, lN = 0.f, d0 = 0.f, d1 = 0.f, dN = 0.f;
    float c0 = 0.f, c1v = 0.f, cN = 0.f, q0 = 0.f, qN = 0.f;
#pragma unroll
    for (int k = 0; k < 8; ++k) {
        if (k < 7 || t < 104) {
            int j = t + 128 * k;
            float y = fmaf((float)j, DYF, 0.001f);
            float u = 1.f - y * y;
            float iL, iD, vc;
            point_all(c, U, y, u, iL, iD, vc);
            float y2 = fmaf((float)j, DY2F, 0.001f);
            float vd = point_Vd(c, U, y2);
            sL += iL; sD += iD; sc += vc; sd += vd;
            if (k == 0) {
                if (t == 0) { l0 = iL; d0 = iD; c0 = vc; q0 = vd; }
                if (t == 1) { l1 = iL; d1 = iD; c1v = vc; }
            }
            if (k == 7 && t == 103) { lN = iL; dN = iD; cN = vc; qN = vd; }
        }
    }
#pragma unroll
    for (int o = 32; o > 0; o >>= 1) {
        sL += __shfl_xor(sL, o, 64);
        sD += __shfl_xor(sD, o, 64);
        sc += __shfl_xor(sc, o, 64);
        sd += __shfl_xor(sd, o, 64);
    }
    if (lane == 0) { red[w] = sL; red[2 + w] = sD; red[4 + w] = sc; red[6 + w] = sd; }
    if (t == 0)   { spx[0] = l0; spx[3] = d0; spx[6] = c0; spx[9]  = q0; }
    if (t == 1)   { spx[1] = l1; spx[4] = d1; spx[7] = c1v; }
    if (t == 103) { spx[2] = lN; spx[5] = dN; spx[8] = cN; spx[10] = qN; }
    __syncthreads();
    if (t == 0) {
        float SL = red[0] + red[1], SD = red[2] + red[3];
        float Sc = red[4] + red[5], Sd = red[6] + red[7];
        float Lv  = 4.f * zq * trapz_ext(SL, spx[0], spx[1], spx[2]) / PI_F;
        float dLv = trapz_ext(SD, spx[3], spx[4], spx[5]) / PI_F;
        float Vcn = c.coef * PI_F * 4.f * trapz_ext(Sc, spx[6], spx[7], spx[8]) * frcp(zq);
        float Vd  = c.coef * PI_F * 2.f * (1.f - zq) * trapz_d(Sd, spx[9], spx[10]);
        ws[16 + i] = dLv;
        ws[16 + NG + i] = Vcn - Vd;
        ws[16 + 2 * NG + i] = Lv;
    }
}

// ---------------------------------------------------------------------------
// Kernel B: 1-block table scan (sign crossings -> bound, L_crit).
// ---------------------------------------------------------------------------
__global__ __launch_bounds__(256) void scan_kernel(float* ws) {
    __shared__ int sdl, sv;
    const float* dLbuf = ws + 16;
    const float* Vbuf  = ws + 16 + NG;
    const float* Lbuf  = ws + 16 + 2 * NG;
    int t = threadIdx.x;
    if (t == 0) { sdl = NG; sv = NG; }
    __syncthreads();
#pragma unroll
    for (int r = 0; r < NG / 256; ++r) {
        int i = t + 256 * r;
        float dcur = dLbuf[i];
        float dprev = (i > 0) ? dLbuf[i - 1] : 1.f;     // dL(lo) >= 0 invariant
        if (dcur < 0.f && dprev >= 0.f) atomicMin(&sdl, i);
        float vcur = Vbuf[i];
        float vprev = (i > 0) ? Vbuf[i - 1] : -1.f;     // V(lo) <= 0 invariant
        if (vcur > 0.f && vprev <= 0.f) atomicMin(&sv, i);
    }
    __syncthreads();
    if (t == 0) {
        int bound = sdl, iv = sv;
        float Lcrit;
        if (bound < 2) {
            Lcrit = -1.f;                       // degenerate: everything invalid
        } else if (iv >= NG || iv >= bound) {
            Lcrit = Lbuf[bound - 1];            // no crossing in range -> ~L_max
        } else if (iv == 0) {
            float z0 = 0.001f + 0.5f * HG;
            Lcrit = Lbuf[0] * 0.001f * frcp(z0);   // crossing at lo endpoint
        } else {
            float zhi = fmaf((float)iv + 0.5f, HG, 0.001f);
            float zlo = zhi - HG;
            float vhi = Vbuf[iv], vlo = Vbuf[iv - 1];
            float zc = zlo - vlo * (zhi - zlo) * frcp(fmaxf(vhi - vlo, 1e-30f));
            zc = fminf(fmaxf(zc, zlo), zhi);
            float tt = (zc - 0.001f) * frcp(HG) - 0.5f;
            int i0 = (int)tt;
            i0 = max(0, min(i0, bound - 2));
            float frac = fminf(fmaxf(tt - (float)i0, 0.f), 1.f);
            Lcrit = Lbuf[i0] + frac * (Lbuf[i0 + 1] - Lbuf[i0]);
        }
        ws[0] = Lcrit;
        ws[1] = (float)bound;
    }
}

// ---------------------------------------------------------------------------
// Kernel C: per-element (R19 structure unchanged): Hermite inversion of
// (L, dL) -> zs; fast path zs >= ZT interpolates the V table (cubic
// Lagrange); rare zs < ZT run the exact 2-wave quadrature.
// ---------------------------------------------------------------------------
__global__ __launch_bounds__(128) void elem_v_kernel(
        const float* Ls, const float* a, const float* b, const float* lc,
        const float* ws, float* out, int B) {
    __shared__ float red[4];
    __shared__ float spx[8];
    int wid = blockIdx.x;
    int t = threadIdx.x, lane = t & 63, w = t >> 6;
    if (wid >= B) return;

    float L_crit = ws[0];
    int bound = (int)ws[1];
    float Lq = Ls[wid];
    if (!(Lq < L_crit) || bound < 2) {   // invalid row: exact 0
        if (t == 0) out[wid] = 0.f;
        return;
    }

    const float* dLbuf = ws + 16;
    const float* Vbuf  = ws + 16 + NG;
    const float* Lbuf  = ws + 16 + 2 * NG;
    // largest lo in [0, bound) with L[lo] < Lq (block-uniform, redundant)
    int lo = -1, hi = bound - 1;
    while (hi > lo) {
        int mid = (lo + hi + 1) >> 1;
        if (Lbuf[mid] < Lq) lo = mid; else hi = mid - 1;
    }
    float zs;
    if (lo < 0) {
        // below first sample: L ~ linear through origin (rel err ~0.05*zs)
        float z0 = 0.001f + 0.5f * HG;
        zs = z0 * Lq * frcp(fmaxf(Lbuf[0], 1e-20f));
    } else {
        int seg = min(lo, bound - 2);
        float zl = fmaf((float)seg + 0.5f, HG, 0.001f);
        float Ll = Lbuf[seg],  Lh = Lbuf[seg + 1];
        float dl = dLbuf[seg] * HG, dh = dLbuf[seg + 1] * HG;  // d/ds scale
        float s = fminf(fmaxf((Lq - Ll) * frcp(fmaxf(Lh - Ll, 1e-20f)), 0.f), 1.f);
#pragma unroll
        for (int it = 0; it < 2; ++it) {
            float s2 = s * s, s3 = s2 * s;
            float H  = (2.f*s3 - 3.f*s2 + 1.f) * Ll + (s3 - 2.f*s2 + s) * dl
                     + (-2.f*s3 + 3.f*s2) * Lh + (s3 - s2) * dh;
            float Hp = (6.f*s2 - 6.f*s) * (Ll - Lh)
                     + (3.f*s2 - 4.f*s + 1.f) * dl + (3.f*s2 - 2.f*s) * dh;
            float step = (H - Lq) * frcp(Hp);
            if (fabsf(Hp) > 1e-20f) s = fminf(fmaxf(s - step, 0.f), 1.f);
        }
        zs = fmaf(s, HG, zl);
    }
    zs = fminf(fmaxf(zs, 1e-4f), 0.9995f);

    // fast path: cubic Lagrange interp of the V table (block-uniform branch)
    if (zs >= ZT) {
        if (t == 0) {
            float tt = (zs - 0.001f) * frcp(HG) - 0.5f;
            int i0 = (int)tt;
            i0 = max(1, min(i0, NG - 3));
            float s = tt - (float)i0;
            float vm = Vbuf[i0 - 1], v0 = Vbuf[i0], v1 = Vbuf[i0 + 1], v2 = Vbuf[i0 + 2];
            float wm = -s * (s - 1.f) * (s - 2.f) * (1.f / 6.f);
            float w0 = (s + 1.f) * (s - 1.f) * (s - 2.f) * 0.5f;
            float w1 = -(s + 1.f) * s * (s - 2.f) * 0.5f;
            float w2 = (s + 1.f) * s * (s - 1.f) * (1.f / 6.f);
            out[wid] = wm * vm + w0 * v0 + w1 * v1 + w2 * v2;
        }
        return;
    }

    // slow path (~0.3% of elements): exact V quadrature (8 pts/lane x 2 waves)
    Co c = make_co(a, b, lc);
    Uni U = make_uni(c, zs);
    float sc = 0.f, sd = 0.f, c0 = 0.f, c1v = 0.f, cN = 0.f, q0 = 0.f, qN = 0.f;
#pragma unroll
    for (int k = 0; k < 8; ++k) {
        if (k < 7 || t < 104) {
            int j = t + 128 * k;
            float y = fmaf((float)j, DYF, 0.001f);
            float u = 1.f - y * y;
            float vc = point_Vc(c, U, y, u);
            float y2 = fmaf((float)j, DY2F, 0.001f);
            float vd = point_Vd(c, U, y2);
            sc += vc; sd += vd;
            if (k == 0) {
                if (t == 0) { c0 = vc; q0 = vd; }
                if (t == 1) { c1v = vc; }
            }
            if (k == 7 && t == 103) { cN = vc; qN = vd; }
        }
    }
#pragma unroll
    for (int o = 32; o > 0; o >>= 1) {
        sc += __shfl_xor(sc, o, 64);
        sd += __shfl_xor(sd, o, 64);
    }
    if (lane == 0) { red[w] = sc; red[2 + w] = sd; }
    if (t == 0)   { spx[0] = c0; spx[3] = q0; }
    if (t == 1)   { spx[1] = c1v; }
    if (t == 103) { spx[2] = cN; spx[4] = qN; }
    __syncthreads();
    if (t == 0) {
        float Sc = red[0] + red[1], Sd = red[2] + red[3];
        float Vc = c.coef * PI_F * 4.f * trapz_ext(Sc, spx[0], spx[1], spx[2]) * frcp(zs);
        float Vd = c.coef * PI_F * 2.f * (1.f - zs) * trapz_d(Sd, spx[3], spx[4]);
        out[wid] = Vc - Vd;
    }
}

// ---------------------------------------------------------------------------
extern "C" void kernel_launch(void* const* d_in, const int* in_sizes, int n_in,
                              void* d_out, int out_size, void* d_ws, size_t ws_size,
                              hipStream_t stream) {
    const float* Ls = (const float*)d_in[0];
    const float* a  = (const float*)d_in[1];
    const float* b  = (const float*)d_in[2];
    const float* lc = (const float*)d_in[3];
    float* out = (float*)d_out;
    float* ws  = (float*)d_ws;
    int B = in_sizes[0];

    grid_eval_kernel<<<NG, 128, 0, stream>>>(a, b, lc, ws);
    scan_kernel<<<1, 256, 0, stream>>>(ws);
    elem_v_kernel<<<B, 128, 0, stream>>>(Ls, a, b, lc, ws, out, B);
}